// Round 2
// baseline (1112.682 us; speedup 1.0000x reference)
//
#include <hip/hip_runtime.h>
#include <hip/hip_bf16.h>
#include <math.h>

#define NNODES 100000
#define NEDGES 800000
#define HDIM 64
#define CDIM 10
#define NLAYERS 3
#define NGRAPH 500
#define CAP 40
#define OVFCAP 4096
#define BN_EPS 1e-5f
#define TN 128              // nodes per GEMM block tile

// ---------------- CSR build (bucketed, fixed capacity + overflow list) ----------------
__global__ void fill_buckets(const int* __restrict__ src, const int* __restrict__ dst,
                             unsigned* __restrict__ cnt, int* __restrict__ csr,
                             unsigned* __restrict__ ovfcnt, int* __restrict__ ovf) {
    int e = blockIdx.x * blockDim.x + threadIdx.x;
    if (e >= NEDGES) return;
    int d = dst[e];
    unsigned slot = atomicAdd(&cnt[d], 1u);
    if (slot < CAP) {
        csr[(size_t)d * CAP + slot] = src[e];
    } else {
        unsigned o = atomicAdd(ovfcnt, 1u);
        if (o < OVFCAP) { ovf[2*o] = src[e]; ovf[2*o+1] = d; }
    }
}

// -------- aggregation: 4 nodes per wave (16-lane groups, float4/lane), idx prefetch ---
__global__ void aggregate4(const float* __restrict__ hin, const unsigned* __restrict__ cnt,
                           const int* __restrict__ csr, float* __restrict__ M) {
    int tid = threadIdx.x;
    int g   = (tid >> 4) & 3;       // group within wave
    int sub = tid & 15;             // lane within group: float4 column
    int node = blockIdx.x * 16 + ((tid >> 6) << 2) + g;
    if (node >= NNODES) return;
    unsigned deg = cnt[node]; if (deg > CAP) deg = CAP;
    const int* lst = csr + (size_t)node * CAP;
    const float4* h4 = (const float4*)hin;
    float4 acc = make_float4(0.f, 0.f, 0.f, 0.f);
    unsigned e = 0;
    for (; e + 4 <= deg; e += 4) {
        int s0 = lst[e], s1 = lst[e+1], s2 = lst[e+2], s3 = lst[e+3];
        float4 v0 = h4[(size_t)s0*16 + sub];
        float4 v1 = h4[(size_t)s1*16 + sub];
        float4 v2 = h4[(size_t)s2*16 + sub];
        float4 v3 = h4[(size_t)s3*16 + sub];
        acc.x += v0.x + v1.x + v2.x + v3.x;
        acc.y += v0.y + v1.y + v2.y + v3.y;
        acc.z += v0.z + v1.z + v2.z + v3.z;
        acc.w += v0.w + v1.w + v2.w + v3.w;
    }
    for (; e < deg; ++e) {
        float4 v = h4[(size_t)lst[e]*16 + sub];
        acc.x += v.x; acc.y += v.y; acc.z += v.z; acc.w += v.w;
    }
    ((float4*)M)[(size_t)node*16 + sub] = acc;
}

// overflow edges (should be zero, but correctness-safe)
__global__ void ovf_add(const float* __restrict__ hin, const unsigned* __restrict__ ovfcnt,
                        const int* __restrict__ ovf, float* __restrict__ M) {
    unsigned n = *ovfcnt; if (n > OVFCAP) n = OVFCAP;
    unsigned total = n * HDIM;
    for (unsigned t = threadIdx.x; t < total; t += blockDim.x) {
        unsigned o = t >> 6; int j = t & 63;
        int s = ovf[2*o], d = ovf[2*o+1];
        atomicAdd(&M[(size_t)d*HDIM + j], hin[(size_t)s*HDIM + j]);
    }
}

// ---------------- fallback: pure atomic scatter (if ws too small for CSR) -----------
__global__ void scatter_atomic(const float* __restrict__ hin, const int* __restrict__ src,
                               const int* __restrict__ dst, float* __restrict__ M) {
    long long t = (long long)blockIdx.x * blockDim.x + threadIdx.x;
    if (t >= (long long)NEDGES * HDIM) return;
    int e = (int)(t >> 6), j = (int)(t & 63);
    atomicAdd(&M[(size_t)dst[e]*HDIM + j], hin[(size_t)src[e]*HDIM + j]);
}

// ------- Linear+BN+ELU as register-blocked tiled GEMM: 128x64 tile, 8x4 per thread ----
__global__ __launch_bounds__(256) void gemm_bn_elu(
        const float* __restrict__ M, float* __restrict__ hout,
        const float* __restrict__ Ws, const float* __restrict__ bs,
        const float* __restrict__ gammas, const float* __restrict__ betas,
        const float* __restrict__ means, const float* __restrict__ vars_,
        int layer) {
    __shared__ float Ml[TN][68];      // pad 68: stride-17 in float4 chunks, conflict-free
    __shared__ float Wl[HDIM][HDIM];
    int tid = threadIdx.x;

    // stage W (64x64)
    const float4* Wg4 = (const float4*)(Ws + (size_t)layer*HDIM*HDIM);
    float4* Wl4 = (float4*)Wl;
    #pragma unroll
    for (int r = 0; r < 4; ++r) Wl4[tid + r*256] = Wg4[tid + r*256];

    // stage M tile (128x64), coalesced float4
    int base = blockIdx.x * TN;
    const float4* M4 = (const float4*)M;
    #pragma unroll
    for (int r = 0; r < 8; ++r) {
        int f = tid + 256*r;
        int row = f >> 4, c4 = f & 15;
        int gr = base + row;
        float4 v = (gr < NNODES) ? M4[(size_t)gr*16 + c4]
                                 : make_float4(0.f,0.f,0.f,0.f);
        *(float4*)&Ml[row][c4*4] = v;
    }
    __syncthreads();

    int tx = tid & 15;        // node group: rows tx + 16*i
    int ty = tid >> 4;        // col group: cols 4*ty .. 4*ty+3
    float acc[8][4];
    #pragma unroll
    for (int i = 0; i < 8; ++i)
        #pragma unroll
        for (int j = 0; j < 4; ++j) acc[i][j] = 0.f;

    #pragma unroll
    for (int k4 = 0; k4 < 16; ++k4) {
        float4 b0 = *(const float4*)&Wl[4*k4+0][ty*4];
        float4 b1 = *(const float4*)&Wl[4*k4+1][ty*4];
        float4 b2 = *(const float4*)&Wl[4*k4+2][ty*4];
        float4 b3 = *(const float4*)&Wl[4*k4+3][ty*4];
        #pragma unroll
        for (int i = 0; i < 8; ++i) {
            float4 a = *(const float4*)&Ml[tx + 16*i][k4*4];
            acc[i][0] += a.x*b0.x + a.y*b1.x + a.z*b2.x + a.w*b3.x;
            acc[i][1] += a.x*b0.y + a.y*b1.y + a.z*b2.y + a.w*b3.y;
            acc[i][2] += a.x*b0.z + a.y*b1.z + a.z*b2.z + a.w*b3.z;
            acc[i][3] += a.x*b0.w + a.y*b1.w + a.z*b2.w + a.w*b3.w;
        }
    }

    // epilogue: +bias, BN (folded scale/shift), ELU, store
    float sc[4], sh[4];
    #pragma unroll
    for (int j = 0; j < 4; ++j) {
        int c = ty*4 + j;
        float b  = bs[layer*HDIM + c];
        float gm = gammas[layer*HDIM + c];
        float be = betas[layer*HDIM + c];
        float mu = means[layer*HDIM + c];
        float vv = vars_[layer*HDIM + c];
        float s  = gm * rsqrtf(vv + BN_EPS);
        sc[j] = s;
        sh[j] = (b - mu) * s + be;
    }
    float4* H4 = (float4*)hout;
    #pragma unroll
    for (int i = 0; i < 8; ++i) {
        int node = base + tx + 16*i;
        if (node >= NNODES) continue;
        float4 o;
        float y0 = acc[i][0]*sc[0] + sh[0]; o.x = (y0 > 0.f) ? y0 : expm1f(y0);
        float y1 = acc[i][1]*sc[1] + sh[1]; o.y = (y1 > 0.f) ? y1 : expm1f(y1);
        float y2 = acc[i][2]*sc[2] + sh[2]; o.z = (y2 > 0.f) ? y2 : expm1f(y2);
        float y3 = acc[i][3]*sc[3] + sh[3]; o.w = (y3 > 0.f) ? y3 : expm1f(y3);
        H4[(size_t)node*16 + ty] = o;
    }
}

// ---------------- logits -> entropy per node + global max ---------------------------
__global__ void classify(const float* __restrict__ H, const float* __restrict__ Wc,
                         const float* __restrict__ bc, float* __restrict__ Hent,
                         unsigned* __restrict__ maxH) {
    __shared__ float Wl[HDIM*CDIM];
    __shared__ float bl[CDIM];
    int tid = threadIdx.x;
    for (int idx = tid; idx < HDIM*CDIM; idx += blockDim.x) Wl[idx] = Wc[idx];
    if (tid < CDIM) bl[tid] = bc[tid];
    __syncthreads();

    int i = blockIdx.x * blockDim.x + tid;
    if (i >= NNODES) return;
    const float4* hr = (const float4*)(H + (size_t)i*HDIM);
    float lg[CDIM];
    #pragma unroll
    for (int c = 0; c < CDIM; ++c) lg[c] = bl[c];
    #pragma unroll
    for (int q = 0; q < HDIM/4; ++q) {
        float4 v = hr[q];
        #pragma unroll
        for (int kk = 0; kk < 4; ++kk) {
            float x = (&v.x)[kk];
            int k = q*4 + kk;
            #pragma unroll
            for (int c = 0; c < CDIM; ++c) lg[c] += x * Wl[k*CDIM + c];
        }
    }
    float mx = lg[0];
    #pragma unroll
    for (int c = 1; c < CDIM; ++c) mx = fmaxf(mx, lg[c]);
    float se = 0.f, dot = 0.f;
    #pragma unroll
    for (int c = 0; c < CDIM; ++c) { float e = expf(lg[c]-mx); se += e; dot += e*lg[c]; }
    float lse = mx + logf(se);
    float Hv = lse - dot/se;
    Hv = fmaxf(Hv, 0.f);
    Hent[i] = Hv;
    atomicMax(maxH, __float_as_uint(Hv));
}

// ---------------- per-graph lambda-weighted pooling + final classify ----------------
__global__ void pool_final(const float* __restrict__ H, const float* __restrict__ Hent,
                           const unsigned* __restrict__ maxH, const int* __restrict__ n2g,
                           const float* __restrict__ Wc, const float* __restrict__ bc,
                           float* __restrict__ out) {
    __shared__ float partial[4][HDIM];
    __shared__ float pooled[HDIM];
    int g = blockIdx.x;
    int w = threadIdx.x >> 6, lane = threadIdx.x & 63;

    int lo = 0, hi = NNODES;
    while (lo < hi) { int mid = (lo+hi) >> 1; if (n2g[mid] < g) lo = mid+1; else hi = mid; }
    int start = lo;
    hi = NNODES;
    while (lo < hi) { int mid = (lo+hi) >> 1; if (n2g[mid] < g+1) lo = mid+1; else hi = mid; }
    int end = lo;

    float invMax = 1.0f / __uint_as_float(*maxH);
    float acc = 0.f;
    for (int i = start + w; i < end; i += 4) {
        float lam = 1.0f - Hent[i] * invMax;
        acc += lam * H[(size_t)i*HDIM + lane];
    }
    partial[w][lane] = acc;
    __syncthreads();
    if (w == 0)
        pooled[lane] = partial[0][lane] + partial[1][lane] + partial[2][lane] + partial[3][lane];
    __syncthreads();
    if (threadIdx.x < CDIM) {
        int c = threadIdx.x;
        float s = bc[c];
        for (int k = 0; k < HDIM; ++k) s += pooled[k] * Wc[k*CDIM + c];
        out[g*CDIM + c] = s;
    }
}

extern "C" void kernel_launch(void* const* d_in, const int* in_sizes, int n_in,
                              void* d_out, int out_size, void* d_ws, size_t ws_size,
                              hipStream_t stream) {
    const float* feat  = (const float*)d_in[0];
    const int*   src   = (const int*)d_in[1];
    const int*   dst   = (const int*)d_in[2];
    const int*   n2g   = (const int*)d_in[3];
    const float* Ws    = (const float*)d_in[4];
    const float* bs    = (const float*)d_in[5];
    const float* gam   = (const float*)d_in[6];
    const float* bet   = (const float*)d_in[7];
    const float* mea   = (const float*)d_in[8];
    const float* var_  = (const float*)d_in[9];
    const float* Wc    = (const float*)d_in[10];
    const float* bc    = (const float*)d_in[11];
    float* out = (float*)d_out;

    char* ws = (char*)d_ws;
    size_t off = 0;
    auto take = [&](size_t bytes) {
        char* p = ws + off;
        off += (bytes + 255) & ~(size_t)255;
        return p;
    };

    unsigned* cnt    = (unsigned*)take((size_t)NNODES*4);
    unsigned* ovfcnt = (unsigned*)take(4);
    int*      ovf    = (int*)take((size_t)OVFCAP*2*4);
    unsigned* maxH   = (unsigned*)take(4);
    float*    M      = (float*)take((size_t)NNODES*HDIM*4);
    float*    Hbuf   = (float*)take((size_t)NNODES*HDIM*4);
    float*    Hent   = (float*)take((size_t)NNODES*4);
    size_t base_need = off;
    int*      csr    = (int*)take((size_t)NNODES*CAP*4);
    size_t csr_need = off;

    bool use_csr = (ws_size >= csr_need);

    hipMemsetAsync(maxH, 0, 4, stream);

    int gemm_grid = (NNODES + TN - 1) / TN;

    if (use_csr) {
        hipMemsetAsync(cnt, 0, (size_t)NNODES*4, stream);
        hipMemsetAsync(ovfcnt, 0, 4, stream);
        fill_buckets<<<(NEDGES+255)/256, 256, 0, stream>>>(src, dst, cnt, csr, ovfcnt, ovf);
        const float* hin = feat;
        for (int l = 0; l < NLAYERS; ++l) {
            aggregate4<<<(NNODES+15)/16, 256, 0, stream>>>(hin, cnt, csr, M);
            ovf_add<<<1, 256, 0, stream>>>(hin, ovfcnt, ovf, M);
            gemm_bn_elu<<<gemm_grid, 256, 0, stream>>>(M, Hbuf, Ws, bs, gam, bet, mea, var_, l);
            hin = Hbuf;
        }
    } else if (ws_size >= base_need) {
        const float* hin = feat;
        for (int l = 0; l < NLAYERS; ++l) {
            hipMemsetAsync(M, 0, (size_t)NNODES*HDIM*4, stream);
            long long tot = (long long)NEDGES * HDIM;
            scatter_atomic<<<(unsigned)((tot + 255)/256), 256, 0, stream>>>(hin, src, dst, M);
            gemm_bn_elu<<<gemm_grid, 256, 0, stream>>>(M, Hbuf, Ws, bs, gam, bet, mea, var_, l);
            hin = Hbuf;
        }
    }

    classify<<<(NNODES+255)/256, 256, 0, stream>>>(Hbuf, Wc, bc, Hent, maxH);
    pool_final<<<NGRAPH, 256, 0, stream>>>(Hbuf, Hent, maxH, n2g, Wc, bc, out);
}

// Round 3
// 284.851 us; speedup vs baseline: 3.9062x; 3.9062x over previous
//
#include <hip/hip_runtime.h>
#include <hip/hip_bf16.h>
#include <math.h>

#define NNODES 100000
#define NEDGES 800000
#define HDIM 64
#define CDIM 10
#define NLAYERS 3
#define NGRAPH 500
#define CAP 40
#define OVFCAP 4096
#define BN_EPS 1e-5f
#define TN 64               // nodes per GEMM block tile

// ---------------- CSR build (bucketed, fixed capacity + overflow list) ----------------
__global__ void fill_buckets(const int* __restrict__ src, const int* __restrict__ dst,
                             unsigned* __restrict__ cnt, int* __restrict__ csr,
                             unsigned* __restrict__ ovfcnt, int* __restrict__ ovf) {
    int e = blockIdx.x * blockDim.x + threadIdx.x;
    if (e >= NEDGES) return;
    int d = dst[e];
    unsigned slot = atomicAdd(&cnt[d], 1u);
    if (slot < CAP) {
        csr[(size_t)d * CAP + slot] = src[e];
    } else {
        unsigned o = atomicAdd(ovfcnt, 1u);
        if (o < OVFCAP) { ovf[2*o] = src[e]; ovf[2*o+1] = d; }
    }
}

// -------- aggregation: 4 nodes per wave (16-lane groups, float4/lane), idx prefetch ---
__global__ void aggregate4(const float* __restrict__ hin, const unsigned* __restrict__ cnt,
                           const int* __restrict__ csr, float* __restrict__ M) {
    int tid = threadIdx.x;
    int g   = (tid >> 4) & 3;       // group within wave
    int sub = tid & 15;             // lane within group: float4 column
    int node = blockIdx.x * 16 + ((tid >> 6) << 2) + g;
    if (node >= NNODES) return;
    unsigned deg = cnt[node]; if (deg > CAP) deg = CAP;
    const int* lst = csr + (size_t)node * CAP;
    const float4* h4 = (const float4*)hin;
    float4 acc = make_float4(0.f, 0.f, 0.f, 0.f);
    unsigned e = 0;
    for (; e + 4 <= deg; e += 4) {
        int s0 = lst[e], s1 = lst[e+1], s2 = lst[e+2], s3 = lst[e+3];
        float4 v0 = h4[(size_t)s0*16 + sub];
        float4 v1 = h4[(size_t)s1*16 + sub];
        float4 v2 = h4[(size_t)s2*16 + sub];
        float4 v3 = h4[(size_t)s3*16 + sub];
        acc.x += v0.x + v1.x + v2.x + v3.x;
        acc.y += v0.y + v1.y + v2.y + v3.y;
        acc.z += v0.z + v1.z + v2.z + v3.z;
        acc.w += v0.w + v1.w + v2.w + v3.w;
    }
    for (; e < deg; ++e) {
        float4 v = h4[(size_t)lst[e]*16 + sub];
        acc.x += v.x; acc.y += v.y; acc.z += v.z; acc.w += v.w;
    }
    ((float4*)M)[(size_t)node*16 + sub] = acc;
}

// overflow edges (should be zero, but correctness-safe)
__global__ void ovf_add(const float* __restrict__ hin, const unsigned* __restrict__ ovfcnt,
                        const int* __restrict__ ovf, float* __restrict__ M) {
    unsigned n = *ovfcnt; if (n > OVFCAP) n = OVFCAP;
    unsigned total = n * HDIM;
    for (unsigned t = threadIdx.x; t < total; t += blockDim.x) {
        unsigned o = t >> 6; int j = t & 63;
        int s = ovf[2*o], d = ovf[2*o+1];
        atomicAdd(&M[(size_t)d*HDIM + j], hin[(size_t)s*HDIM + j]);
    }
}

// ---------------- fallback: pure atomic scatter (if ws too small for CSR) -----------
__global__ void scatter_atomic(const float* __restrict__ hin, const int* __restrict__ src,
                               const int* __restrict__ dst, float* __restrict__ M) {
    long long t = (long long)blockIdx.x * blockDim.x + threadIdx.x;
    if (t >= (long long)NEDGES * HDIM) return;
    int e = (int)(t >> 6), j = (int)(t & 63);
    atomicAdd(&M[(size_t)dst[e]*HDIM + j], hin[(size_t)src[e]*HDIM + j]);
}

// ------- Linear+BN+ELU tiled GEMM: 64x64 tile, 4x4 per thread, bounded unroll --------
__global__ __launch_bounds__(256, 4) void gemm_bn_elu(
        const float* __restrict__ M, float* __restrict__ hout,
        const float* __restrict__ Ws, const float* __restrict__ bs,
        const float* __restrict__ gammas, const float* __restrict__ betas,
        const float* __restrict__ means, const float* __restrict__ vars_,
        int layer) {
    __shared__ float Ml[TN][68];      // stride 68: worst 2-way bank alias (free)
    __shared__ float Wl[HDIM][68];
    int tid = threadIdx.x;

    // stage W (64x64), coalesced float4
    const float4* Wg4 = (const float4*)(Ws + (size_t)layer*HDIM*HDIM);
    #pragma unroll
    for (int r = 0; r < 4; ++r) {
        int f = tid + 256*r;
        int row = f >> 4, c4 = f & 15;
        *(float4*)&Wl[row][c4*4] = Wg4[f];
    }

    // stage M tile (64x64), coalesced float4
    int base = blockIdx.x * TN;
    const float4* M4 = (const float4*)M;
    #pragma unroll
    for (int r = 0; r < 4; ++r) {
        int f = tid + 256*r;
        int row = f >> 4, c4 = f & 15;
        int gr = base + row;
        float4 v = (gr < NNODES) ? M4[(size_t)gr*16 + c4]
                                 : make_float4(0.f,0.f,0.f,0.f);
        *(float4*)&Ml[row][c4*4] = v;
    }
    __syncthreads();

    int tx = tid & 15;        // node group: rows tx + 16*i, i=0..3
    int ty = tid >> 4;        // col group: cols 4*ty .. 4*ty+3
    float acc[4][4];
    #pragma unroll
    for (int i = 0; i < 4; ++i)
        #pragma unroll
        for (int j = 0; j < 4; ++j) acc[i][j] = 0.f;

    #pragma unroll 4
    for (int k4 = 0; k4 < 16; ++k4) {
        float4 b0 = *(const float4*)&Wl[4*k4+0][ty*4];
        float4 b1 = *(const float4*)&Wl[4*k4+1][ty*4];
        float4 b2 = *(const float4*)&Wl[4*k4+2][ty*4];
        float4 b3 = *(const float4*)&Wl[4*k4+3][ty*4];
        #pragma unroll
        for (int i = 0; i < 4; ++i) {
            float4 a = *(const float4*)&Ml[tx + 16*i][k4*4];
            acc[i][0] += a.x*b0.x + a.y*b1.x + a.z*b2.x + a.w*b3.x;
            acc[i][1] += a.x*b0.y + a.y*b1.y + a.z*b2.y + a.w*b3.y;
            acc[i][2] += a.x*b0.z + a.y*b1.z + a.z*b2.z + a.w*b3.z;
            acc[i][3] += a.x*b0.w + a.y*b1.w + a.z*b2.w + a.w*b3.w;
        }
    }

    // epilogue: +bias, BN (folded scale/shift), ELU, store
    float sc[4], sh[4];
    #pragma unroll
    for (int j = 0; j < 4; ++j) {
        int c = ty*4 + j;
        float b  = bs[layer*HDIM + c];
        float gm = gammas[layer*HDIM + c];
        float be = betas[layer*HDIM + c];
        float mu = means[layer*HDIM + c];
        float vv = vars_[layer*HDIM + c];
        float s  = gm * rsqrtf(vv + BN_EPS);
        sc[j] = s;
        sh[j] = (b - mu) * s + be;
    }
    float4* H4 = (float4*)hout;
    #pragma unroll
    for (int i = 0; i < 4; ++i) {
        int node = base + tx + 16*i;
        if (node >= NNODES) continue;
        float4 o;
        float y0 = acc[i][0]*sc[0] + sh[0]; o.x = (y0 > 0.f) ? y0 : expm1f(y0);
        float y1 = acc[i][1]*sc[1] + sh[1]; o.y = (y1 > 0.f) ? y1 : expm1f(y1);
        float y2 = acc[i][2]*sc[2] + sh[2]; o.z = (y2 > 0.f) ? y2 : expm1f(y2);
        float y3 = acc[i][3]*sc[3] + sh[3]; o.w = (y3 > 0.f) ? y3 : expm1f(y3);
        H4[(size_t)node*16 + ty] = o;
    }
}

// ---------------- logits -> entropy per node + global max ---------------------------
__global__ void classify(const float* __restrict__ H, const float* __restrict__ Wc,
                         const float* __restrict__ bc, float* __restrict__ Hent,
                         unsigned* __restrict__ maxH) {
    __shared__ float Wl[HDIM*CDIM];
    __shared__ float bl[CDIM];
    int tid = threadIdx.x;
    for (int idx = tid; idx < HDIM*CDIM; idx += blockDim.x) Wl[idx] = Wc[idx];
    if (tid < CDIM) bl[tid] = bc[tid];
    __syncthreads();

    int i = blockIdx.x * blockDim.x + tid;
    if (i >= NNODES) return;
    const float4* hr = (const float4*)(H + (size_t)i*HDIM);
    float lg[CDIM];
    #pragma unroll
    for (int c = 0; c < CDIM; ++c) lg[c] = bl[c];
    #pragma unroll
    for (int q = 0; q < HDIM/4; ++q) {
        float4 v = hr[q];
        #pragma unroll
        for (int kk = 0; kk < 4; ++kk) {
            float x = (&v.x)[kk];
            int k = q*4 + kk;
            #pragma unroll
            for (int c = 0; c < CDIM; ++c) lg[c] += x * Wl[k*CDIM + c];
        }
    }
    float mx = lg[0];
    #pragma unroll
    for (int c = 1; c < CDIM; ++c) mx = fmaxf(mx, lg[c]);
    float se = 0.f, dot = 0.f;
    #pragma unroll
    for (int c = 0; c < CDIM; ++c) { float e = expf(lg[c]-mx); se += e; dot += e*lg[c]; }
    float lse = mx + logf(se);
    float Hv = lse - dot/se;
    Hv = fmaxf(Hv, 0.f);
    Hent[i] = Hv;
    atomicMax(maxH, __float_as_uint(Hv));
}

// ---------------- per-graph lambda-weighted pooling + final classify ----------------
__global__ void pool_final(const float* __restrict__ H, const float* __restrict__ Hent,
                           const unsigned* __restrict__ maxH, const int* __restrict__ n2g,
                           const float* __restrict__ Wc, const float* __restrict__ bc,
                           float* __restrict__ out) {
    __shared__ float partial[4][HDIM];
    __shared__ float pooled[HDIM];
    int g = blockIdx.x;
    int w = threadIdx.x >> 6, lane = threadIdx.x & 63;

    int lo = 0, hi = NNODES;
    while (lo < hi) { int mid = (lo+hi) >> 1; if (n2g[mid] < g) lo = mid+1; else hi = mid; }
    int start = lo;
    hi = NNODES;
    while (lo < hi) { int mid = (lo+hi) >> 1; if (n2g[mid] < g+1) lo = mid+1; else hi = mid; }
    int end = lo;

    float invMax = 1.0f / __uint_as_float(*maxH);
    float acc = 0.f;
    for (int i = start + w; i < end; i += 4) {
        float lam = 1.0f - Hent[i] * invMax;
        acc += lam * H[(size_t)i*HDIM + lane];
    }
    partial[w][lane] = acc;
    __syncthreads();
    if (w == 0)
        pooled[lane] = partial[0][lane] + partial[1][lane] + partial[2][lane] + partial[3][lane];
    __syncthreads();
    if (threadIdx.x < CDIM) {
        int c = threadIdx.x;
        float s = bc[c];
        for (int k = 0; k < HDIM; ++k) s += pooled[k] * Wc[k*CDIM + c];
        out[g*CDIM + c] = s;
    }
}

extern "C" void kernel_launch(void* const* d_in, const int* in_sizes, int n_in,
                              void* d_out, int out_size, void* d_ws, size_t ws_size,
                              hipStream_t stream) {
    const float* feat  = (const float*)d_in[0];
    const int*   src   = (const int*)d_in[1];
    const int*   dst   = (const int*)d_in[2];
    const int*   n2g   = (const int*)d_in[3];
    const float* Ws    = (const float*)d_in[4];
    const float* bs    = (const float*)d_in[5];
    const float* gam   = (const float*)d_in[6];
    const float* bet   = (const float*)d_in[7];
    const float* mea   = (const float*)d_in[8];
    const float* var_  = (const float*)d_in[9];
    const float* Wc    = (const float*)d_in[10];
    const float* bc    = (const float*)d_in[11];
    float* out = (float*)d_out;

    char* ws = (char*)d_ws;
    size_t off = 0;
    auto take = [&](size_t bytes) {
        char* p = ws + off;
        off += (bytes + 255) & ~(size_t)255;
        return p;
    };

    unsigned* cnt    = (unsigned*)take((size_t)NNODES*4);
    unsigned* ovfcnt = (unsigned*)take(4);
    int*      ovf    = (int*)take((size_t)OVFCAP*2*4);
    unsigned* maxH   = (unsigned*)take(4);
    float*    M      = (float*)take((size_t)NNODES*HDIM*4);
    float*    Hbuf   = (float*)take((size_t)NNODES*HDIM*4);
    float*    Hent   = (float*)take((size_t)NNODES*4);
    size_t base_need = off;
    int*      csr    = (int*)take((size_t)NNODES*CAP*4);
    size_t csr_need = off;

    bool use_csr = (ws_size >= csr_need);

    hipMemsetAsync(maxH, 0, 4, stream);

    int gemm_grid = (NNODES + TN - 1) / TN;

    if (use_csr) {
        hipMemsetAsync(cnt, 0, (size_t)NNODES*4, stream);
        hipMemsetAsync(ovfcnt, 0, 4, stream);
        fill_buckets<<<(NEDGES+255)/256, 256, 0, stream>>>(src, dst, cnt, csr, ovfcnt, ovf);
        const float* hin = feat;
        for (int l = 0; l < NLAYERS; ++l) {
            aggregate4<<<(NNODES+15)/16, 256, 0, stream>>>(hin, cnt, csr, M);
            ovf_add<<<1, 256, 0, stream>>>(hin, ovfcnt, ovf, M);
            gemm_bn_elu<<<gemm_grid, 256, 0, stream>>>(M, Hbuf, Ws, bs, gam, bet, mea, var_, l);
            hin = Hbuf;
        }
    } else if (ws_size >= base_need) {
        const float* hin = feat;
        for (int l = 0; l < NLAYERS; ++l) {
            hipMemsetAsync(M, 0, (size_t)NNODES*HDIM*4, stream);
            long long tot = (long long)NEDGES * HDIM;
            scatter_atomic<<<(unsigned)((tot + 255)/256), 256, 0, stream>>>(hin, src, dst, M);
            gemm_bn_elu<<<gemm_grid, 256, 0, stream>>>(M, Hbuf, Ws, bs, gam, bet, mea, var_, l);
            hin = Hbuf;
        }
    }

    classify<<<(NNODES+255)/256, 256, 0, stream>>>(Hbuf, Wc, bc, Hent, maxH);
    pool_final<<<NGRAPH, 256, 0, stream>>>(Hbuf, Hent, maxH, n2g, Wc, bc, out);
}